// Round 9
// baseline (321.162 us; speedup 1.0000x reference)
//
#include <hip/hip_runtime.h>
#include <cstdint>

// ---------------- problem constants ----------------
static constexpr int B_  = 8192;
static constexpr int NW_ = 192;                 // NS + NV

typedef __attribute__((ext_vector_type(8))) _Float16 h8v;
typedef __attribute__((ext_vector_type(2))) _Float16 h2v;
typedef __attribute__((ext_vector_type(4))) float f4v;
typedef __attribute__((ext_vector_type(2))) float f2v;
typedef __attribute__((ext_vector_type(4))) unsigned u4v;

#define DI __device__ __forceinline__

DI h2v uh(unsigned u) { return __builtin_bit_cast(h2v, u); }
DI unsigned hu(h2v h) { return __builtin_bit_cast(unsigned, h); }
DI h2v hsplat(unsigned short bits) {
  _Float16 v = __builtin_bit_cast(_Float16, bits);
  h2v t; t.x = v; t.y = v; return t;
}
DI unsigned hpack(float lo, float hi) {       // 2x f32 -> packed f16 (prep/staging only)
  h2v t; t.x = (_Float16)lo; t.y = (_Float16)hi;
  return __builtin_bit_cast(unsigned, t);
}
DI short f2h_bits(float f) { return __builtin_bit_cast(short, (_Float16)f); }

DI f4v mfma16h(h8v a, h8v b, f4v c) {
  return __builtin_amdgcn_mfma_f32_16x16x32_f16(a, b, c, 0, 0, 0);
}

// ---------------- prep: scalar-path weights (f16 frags) ----------------
// layout: wf[(s*12 + F)*512 + lane*8 + j], F = frag 0..11   [verified r7]
//   k = s*32 + (lane>>4)*8 + j ; n = F*16 + (lane&15)
__global__ void prep_wsc(const float* __restrict__ w000, const float* __restrict__ w110,
                         short* __restrict__ wf) {
  int g = blockIdx.x * blockDim.x + threadIdx.x;  // 640*12*64 = 491520 threads
  int lane = g & 63;
  int rest = g >> 6;
  int F = rest % 12;
  int s = rest / 12;
  int n = F * 16 + (lane & 15);
  int kbase = s * 32 + ((lane >> 4) << 3);
  const float s000 = 1.0f / (128.0f * 1.41421356237f);   // (1/N0) * inv_sqrt2
  const float s110 = 1.0f / (64.0f * 2.44948974968f);    // (1/(N1*sqrt3)) * inv_sqrt2
  short o[8];
#pragma unroll
  for (int j = 0; j < 8; ++j) {
    int k = kbase + j;
    float v = (k < 16384) ? w000[(size_t)k * NW_ + n] * s000
                          : w110[(size_t)(k - 16384) * NW_ + n] * s110;
    o[j] = f2h_bits(v);
  }
  *(h8v*)(wf + ((size_t)s * 12 + F) * 512 + lane * 8) = *(h8v*)o;
}

// ---------------- prep: vector-path weights (f16 frags) ----------------
// layout: wf[(s*4 + nf)*512 + lane*8 + j]               [verified r7]
__global__ void prep_wvec(const float* __restrict__ w011, const float* __restrict__ w111,
                          short* __restrict__ wf) {
  int g = blockIdx.x * blockDim.x + threadIdx.x;  // 384*4*64 = 98304 threads
  int lane = g & 63;
  int nf = (g >> 6) & 3;
  int s = g >> 8;
  int n = nf * 16 + (lane & 15);
  int kbase = s * 32 + ((lane >> 4) << 3);
  const float sv = 1.0f / 128.0f;
  short o[8];
#pragma unroll
  for (int j = 0; j < 8; ++j) {
    int k = kbase + j;
    float v = (k < 8192) ? w011[(size_t)k * 64 + n] * sv
                         : w111[(size_t)(k - 8192) * 64 + n] * sv;
    o[j] = f2h_bits(v);
  }
  *(h8v*)(wf + ((size_t)s * 4 + nf) * 512 + lane * 8) = *(h8v*)o;
}

// ---------------- shared LDS staging: 128 rows of x, f16 ----------------
// X0H[row][c]        f16, stride 136 halves
// X1 [row][i*64+v]   f16, stride 200 halves
// total: 128*(136+200)*2 = 86016 B -> 1 block/CU
#define X0H_STRIDE 136
#define X1_STRIDE  200

DI void stage_x(const float* __restrict__ x, int b0,
                unsigned short* X0H, unsigned short* X1) {
  const int t = threadIdx.x;            // 1024 threads, 8 per row
  const int row = t >> 3, l8 = t & 7;
  const float* src = x + (size_t)(b0 + row) * 320;
  unsigned o[8];
#pragma unroll
  for (int j = 0; j < 4; ++j) {
    f4v v = *(const f4v*)(src + l8 * 16 + j * 4);
    o[2 * j]     = hpack(v.x, v.y);
    o[2 * j + 1] = hpack(v.z, v.w);
  }
  *(u4v*)(&X0H[row * X0H_STRIDE + l8 * 16])     = u4v{o[0], o[1], o[2], o[3]};
  *(u4v*)(&X0H[row * X0H_STRIDE + l8 * 16 + 8]) = u4v{o[4], o[5], o[6], o[7]};
  float buf[24];
#pragma unroll
  for (int j = 0; j < 12; ++j) {
    f2v v = *(const f2v*)(src + 128 + l8 * 24 + j * 2);
    buf[2 * j] = v.x; buf[2 * j + 1] = v.y;
  }
#pragma unroll
  for (int i = 0; i < 3; ++i) {
    u4v w;
#pragma unroll
    for (int e = 0; e < 4; ++e)
      w[e] = hpack(buf[(2 * e) * 3 + i], buf[(2 * e + 1) * 3 + i]);
    *(u4v*)(&X1[row * X1_STRIDE + i * 64 + l8 * 8]) = w;
  }
}

// ---------------- A-fragment generators (packed f16) ----------------
DI h8v agen_x0h(const unsigned short* __restrict__ x0r, h2v xu2, int vb) {
  u4v p = *(const u4v*)(x0r + vb);
  u4v pa;
#pragma unroll
  for (int m = 0; m < 4; ++m) pa[m] = hu(uh(p[m]) * xu2);
  return __builtin_bit_cast(h8v, pa);
}
DI h8v agen_dotsh(const unsigned short* __restrict__ x1r, const h2v* us, int vb) {
  u4v p0 = *(const u4v*)(x1r + vb);
  u4v p1 = *(const u4v*)(x1r + 64 + vb);
  u4v p2 = *(const u4v*)(x1r + 128 + vb);
  u4v pa;
#pragma unroll
  for (int m = 0; m < 4; ++m) {
    h2v s = uh(p0[m]) * us[0];
    s = s + uh(p1[m]) * us[1];
    s = s + uh(p2[m]) * us[2];
    pa[m] = hu(s);
  }
  return __builtin_bit_cast(h8v, pa);
}

DI void loadB3(h8v* dst, const short* __restrict__ p) {
#pragma unroll
  for (int nf = 0; nf < 3; ++nf) dst[nf] = *(const h8v*)(p + nf * 512);
}
DI void loadB2(h8v* dst, const short* __restrict__ p) {
#pragma unroll
  for (int nf = 0; nf < 2; ++nf) dst[nf] = *(const h8v*)(p + nf * 512);
}

// ---------------- scalar-path GEMM: C[8192,192] += A(gen) * Wsc ----------------
// grid 256 = 64 mt x 4 kb; block 128 rows x 192 cols, 1024 thr, 16 waves = mg2 x nq4 x kh2
// wave = 4 m-frags x 3 n-frags (12 MFMA per 3KB of B); chunk c = kb*2+kh: 64 x0 + 16 dots
__global__ __launch_bounds__(1024, 4)
void gemm_sc(const float* __restrict__ x, const short* __restrict__ wf,
             float* __restrict__ acc_out) {
  __shared__ unsigned short X0H[128 * X0H_STRIDE];
  __shared__ unsigned short X1[128 * X1_STRIDE];
  const int kb = blockIdx.x & 3;
  const int b0 = (blockIdx.x >> 2) * 128;

  stage_x(x, b0, X0H, X1);
  __syncthreads();

  const int t0 = threadIdx.x;
  const int w = t0 >> 6, lane = t0 & 63;
  const int mg = w & 1, nq = (w >> 1) & 3, kh = w >> 3;
  const int c = kb * 2 + kh;            // chunk 0..7
  const int q = lane >> 4, r = lane & 15, q8 = q * 8;
  // 4 m-frag row pointers: row = mg*64 + f*16 + r
  const unsigned short* x0p[4];
  const unsigned short* x1p[4];
#pragma unroll
  for (int f = 0; f < 4; ++f) {
    int row = mg * 64 + f * 16 + r;
    x0p[f] = &X0H[row * X0H_STRIDE];
    x1p[f] = &X1[row * X1_STRIDE];
  }

  f4v acc[4][3];
#pragma unroll
  for (int f = 0; f < 4; ++f)
#pragma unroll
    for (int nf = 0; nf < 3; ++nf) acc[f][nf] = f4v{0.f, 0.f, 0.f, 0.f};

  // ---- region 1: x0 outer product, 64 steps, s in [c*64, +64) ----
  {
    const int u0 = c * 16;
    const short* wp = wf + ((size_t)(c * 64) * 12 + nq * 3) * 512 + lane * 8;
    for (int g = 0; g < 16; ++g) {
      h2v xu[4];
#pragma unroll
      for (int f = 0; f < 4; ++f) xu[f] = hsplat(x0p[f][u0 + g]);
#pragma unroll
      for (int j = 0; j < 4; ++j) {
        h8v b[3];
        loadB3(b, wp);
        const int vb = j * 32 + q8;
#pragma unroll
        for (int f = 0; f < 4; ++f) {
          h8v a = agen_x0h(x0p[f], xu[f], vb);
#pragma unroll
          for (int nf = 0; nf < 3; ++nf)
            acc[f][nf] = mfma16h(a, b[nf], acc[f][nf]);
        }
        wp += 6144;                      // one K-step = 12 frags x 512
      }
    }
  }

  // ---- region 2: x1-dots, 16 steps, s in [512 + c*16, +16) ----
  {
    const int u0 = c * 8;
    const short* wp = wf + ((size_t)(512 + c * 16) * 12 + nq * 3) * 512 + lane * 8;
    for (int g = 0; g < 8; ++g) {
      const int u = u0 + g;
      h2v us[4][3];
#pragma unroll
      for (int f = 0; f < 4; ++f)
#pragma unroll
        for (int i = 0; i < 3; ++i) us[f][i] = hsplat(x1p[f][i * 64 + u]);
#pragma unroll
      for (int j = 0; j < 2; ++j) {
        h8v b[3];
        loadB3(b, wp);
        const int vb = j * 32 + q8;
#pragma unroll
        for (int f = 0; f < 4; ++f) {
          h8v a = agen_dotsh(x1p[f], us[f], vb);
#pragma unroll
          for (int nf = 0; nf < 3; ++nf)
            acc[f][nf] = mfma16h(a, b[nf], acc[f][nf]);
        }
        wp += 6144;
      }
    }
  }

#pragma unroll
  for (int f = 0; f < 4; ++f)
#pragma unroll
    for (int nf = 0; nf < 3; ++nf) {
      int n = (nq * 3 + nf) * 16 + r;
#pragma unroll
      for (int reg = 0; reg < 4; ++reg) {
        int rowo = b0 + mg * 64 + f * 16 + q * 4 + reg;
        atomicAdd(&acc_out[(size_t)rowo * NW_ + n], acc[f][nf][reg]);
      }
    }
}

// ---------------- vector-path GEMM: C[3*8192, 64] += A(gen) * Wvec ----------------
// grid 256 = 64 mt x 4 kb; block 128 rows x 3 planes x 64 cols, 1024 thr
// 16 waves = mg4 x nh2 x kh2; wave = 2 m-frags x 3 planes x 2 n-frags (12 MFMA / 2KB B)
__global__ __launch_bounds__(1024, 4)
void gemm_vec(const float* __restrict__ x, const short* __restrict__ wf,
              float* __restrict__ acc_out) {
  __shared__ unsigned short X0H[128 * X0H_STRIDE];
  __shared__ unsigned short X1[128 * X1_STRIDE];
  const int kb = blockIdx.x & 3;
  const int b0 = (blockIdx.x >> 2) * 128;

  stage_x(x, b0, X0H, X1);
  __syncthreads();

  const int t0 = threadIdx.x;
  const int w = t0 >> 6, lane = t0 & 63;
  const int mg = w & 3, nh = (w >> 2) & 1, kh = w >> 3;
  const int c = kb * 2 + kh;            // chunk 0..7
  const int q = lane >> 4, r = lane & 15, q8 = q * 8;
  const unsigned short* x0p[2];
  const unsigned short* x1p[2];
#pragma unroll
  for (int f = 0; f < 2; ++f) {
    int row = mg * 32 + f * 16 + r;
    x0p[f] = &X0H[row * X0H_STRIDE];
    x1p[f] = &X1[row * X1_STRIDE];
  }

  f4v acc[2][3][2];
#pragma unroll
  for (int f = 0; f < 2; ++f)
#pragma unroll
    for (int ip = 0; ip < 3; ++ip)
#pragma unroll
      for (int nf = 0; nf < 2; ++nf) acc[f][ip][nf] = f4v{0.f, 0.f, 0.f, 0.f};

  // ---- region 1: x0 * x1[ip], 32 steps, s in [c*32, +32) ----
  {
    const int u0 = c * 16;
    const short* wp = wf + ((size_t)(c * 32) * 4 + nh * 2) * 512 + lane * 8;
    for (int g = 0; g < 16; ++g) {
#pragma unroll
      for (int j = 0; j < 2; ++j) {
        h8v b[2];
        loadB2(b, wp);
        const int vb = j * 32 + q8;
#pragma unroll
        for (int f = 0; f < 2; ++f) {
          h2v xu2 = hsplat(x0p[f][u0 + g]);
#pragma unroll
          for (int i = 0; i < 3; ++i) {
            u4v p = *(const u4v*)(x1p[f] + i * 64 + vb);
            u4v pa;
#pragma unroll
            for (int m = 0; m < 4; ++m) pa[m] = hu(uh(p[m]) * xu2);
            h8v a = __builtin_bit_cast(h8v, pa);
#pragma unroll
            for (int nf = 0; nf < 2; ++nf)
              acc[f][i][nf] = mfma16h(a, b[nf], acc[f][i][nf]);
          }
        }
        wp += 2048;                      // one K-step = 4 frags x 512
      }
    }
  }

  // ---- region 2: cross products, 16 steps, s in [256 + c*16, +16) ----
  {
    const int u0 = c * 8;
    const short* wp = wf + ((size_t)(256 + c * 16) * 4 + nh * 2) * 512 + lane * 8;
    for (int g = 0; g < 8; ++g) {
      const int u = u0 + g;
#pragma unroll
      for (int j = 0; j < 2; ++j) {
        h8v b[2];
        loadB2(b, wp);
        const int vb = j * 32 + q8;
#pragma unroll
        for (int f = 0; f < 2; ++f) {
          h2v us[3];
          u4v p[3];
#pragma unroll
          for (int i = 0; i < 3; ++i) {
            us[i] = hsplat(x1p[f][i * 64 + u]);
            p[i] = *(const u4v*)(x1p[f] + i * 64 + vb);
          }
#pragma unroll
          for (int ip = 0; ip < 3; ++ip) {
            const int i1 = (ip + 1) % 3, i2 = (ip + 2) % 3;
            u4v pa;
#pragma unroll
            for (int m = 0; m < 4; ++m)
              pa[m] = hu(uh(p[i2][m]) * us[i1] - uh(p[i1][m]) * us[i2]);
            h8v a = __builtin_bit_cast(h8v, pa);
#pragma unroll
            for (int nf = 0; nf < 2; ++nf)
              acc[f][ip][nf] = mfma16h(a, b[nf], acc[f][ip][nf]);
          }
        }
        wp += 2048;
      }
    }
  }

#pragma unroll
  for (int f = 0; f < 2; ++f)
#pragma unroll
    for (int ip = 0; ip < 3; ++ip)
#pragma unroll
      for (int nf = 0; nf < 2; ++nf) {
        int n = (nh * 2 + nf) * 16 + r;
#pragma unroll
        for (int reg = 0; reg < 4; ++reg) {
          int rowo = ip * B_ + b0 + mg * 32 + f * 16 + q * 4 + reg;
          atomicAdd(&acc_out[(size_t)rowo * 64 + n], acc[f][ip][nf][reg]);
        }
      }
}

// ---------------- epilogue: silu / sigmoid-gating, interleaved output ----------------
__global__ void epilogue(const float* __restrict__ sc, const float* __restrict__ ve,
                         float* __restrict__ out) {
  int t = blockIdx.x * blockDim.x + threadIdx.x;  // B*192 threads exactly
  int b = t / NW_, c = t % NW_;
  float v = sc[t];
  float sg = 1.0f / (1.0f + __expf(-v));
  if (c < 128) {
    out[(size_t)b * 320 + c] = v * sg;            // silu
  } else {
    int w = c - 128;
#pragma unroll
    for (int i = 0; i < 3; ++i) {
      float vv = ve[((size_t)i * B_ + b) * 64 + w];
      out[(size_t)b * 320 + 128 + w * 3 + i] = vv * sg;
    }
  }
}

// ---------------- launch ----------------
extern "C" void kernel_launch(void* const* d_in, const int* in_sizes, int n_in,
                              void* d_out, int out_size, void* d_ws, size_t ws_size,
                              hipStream_t stream) {
  const float* x    = (const float*)d_in[0];
  const float* w000 = (const float*)d_in[1];
  const float* w110 = (const float*)d_in[2];
  const float* w011 = (const float*)d_in[3];
  const float* w111 = (const float*)d_in[4];
  float* out = (float*)d_out;

  char* ws = (char*)d_ws;
  float* acc_sc = (float*)ws;                     // 8192*192*4  = 6,291,456 B
  float* acc_ve = (float*)(ws + 6291456);         // 3*8192*64*4 = 6,291,456 B
  short* wsc    = (short*)(ws + 12582912);        // 20480*192*2 = 7,864,320 B
  short* wve    = (short*)(ws + 20447232);        // 12288*64*2  = 1,572,864 B

  (void)hipMemsetAsync(acc_sc, 0, 2 * 6291456, stream);  // zero both accumulators
  prep_wsc <<<1920, 256, 0, stream>>>(w000, w110, wsc);
  prep_wvec<<<384,  256, 0, stream>>>(w011, w111, wve);
  gemm_sc  <<<256, 1024, 0, stream>>>(x, wsc, acc_sc);
  gemm_vec <<<256, 1024, 0, stream>>>(x, wve, acc_ve);
  epilogue <<<6144, 256, 0, stream>>>(acc_sc, acc_ve, out);
}

// Round 10
// 242.777 us; speedup vs baseline: 1.3229x; 1.3229x over previous
//
#include <hip/hip_runtime.h>
#include <cstdint>

// ---------------- problem constants ----------------
static constexpr int B_  = 8192;
static constexpr int NW_ = 192;                 // NS + NV

typedef __attribute__((ext_vector_type(8))) _Float16 h8v;
typedef __attribute__((ext_vector_type(2))) _Float16 h2v;
typedef __attribute__((ext_vector_type(4))) float f4v;
typedef __attribute__((ext_vector_type(2))) float f2v;
typedef __attribute__((ext_vector_type(4))) unsigned u4v;

#define DI __device__ __forceinline__

DI h2v uh(unsigned u) { return __builtin_bit_cast(h2v, u); }
DI unsigned hu(h2v h) { return __builtin_bit_cast(unsigned, h); }
DI h2v hsplat(unsigned short bits) {
  _Float16 v = __builtin_bit_cast(_Float16, bits);
  h2v t; t.x = v; t.y = v; return t;
}
DI unsigned hpack(float lo, float hi) {
  h2v t; t.x = (_Float16)lo; t.y = (_Float16)hi;
  return __builtin_bit_cast(unsigned, t);
}
DI short f2h_bits(float f) { return __builtin_bit_cast(short, (_Float16)f); }

DI f4v mfma16h(h8v a, h8v b, f4v c) {
  return __builtin_amdgcn_mfma_f32_16x16x32_f16(a, b, c, 0, 0, 0);
}

// ---- block-symmetry tables (2 bits per block index) ----
// x0 region: 10 blocks over 4x4 grid: (0,0)(1,1)(2,2)(3,3)(0,1)(0,2)(0,3)(1,2)(1,3)(2,3)
static constexpr unsigned PK_BU0 = 606436u;   // {0,1,2,3,0,0,0,1,1,2}
static constexpr unsigned PK_BV0 = 1030628u;  // {0,1,2,3,1,2,3,2,3,3}
// 64-dim regions: 3 blocks: (0,0)(1,1)(0,1)
static constexpr unsigned PK_BU2 = 4u;        // {0,1,0}
static constexpr unsigned PK_BV2 = 20u;       // {0,1,1}
DI int tab2(unsigned pack, int blk) { return (int)((pack >> (2 * blk)) & 3u); }

// ---------------- prep: scalar-path weights (f16 frags, block-symmetrized) ----------------
// layout: wf[(s*12 + F)*512 + lane*8 + j]; s in [0,416)
//   s<320: x0x0 pairs; s>=320: x1-dots pairs (sp = s-320 in [0,96))
__global__ void prep_wsc(const float* __restrict__ w000, const float* __restrict__ w110,
                         short* __restrict__ wf) {
  int g = blockIdx.x * blockDim.x + threadIdx.x;  // 416*12*64 = 319488 threads
  int lane = g & 63;
  int rest = g >> 6;
  int F = rest % 12;
  int s = rest / 12;
  int n = F * 16 + (lane & 15);
  int kk0 = (lane >> 4) << 3;
  const float s000 = 1.0f / (128.0f * 1.41421356237f);   // (1/N0) * inv_sqrt2
  const float s110 = 1.0f / (64.0f * 2.44948974968f);    // (1/(N1*sqrt3)) * inv_sqrt2
  short o[8];
  if (s < 320) {
    int blk = s >> 5, ik = s & 31;
    int bu = tab2(PK_BU0, blk), bv = tab2(PK_BV0, blk);
    int u = bu * 32 + ik;
#pragma unroll
    for (int j = 0; j < 8; ++j) {
      int v = bv * 32 + kk0 + j;
      float val = w000[(size_t)(u * 128 + v) * NW_ + n];
      if (bu != bv) val += w000[(size_t)(v * 128 + u) * NW_ + n];
      o[j] = f2h_bits(val * s000);
    }
  } else {
    int sp = s - 320;
    int blk = sp >> 5, ik = sp & 31;
    int bu = tab2(PK_BU2, blk), bv = tab2(PK_BV2, blk);
    int u = bu * 32 + ik;
#pragma unroll
    for (int j = 0; j < 8; ++j) {
      int v = bv * 32 + kk0 + j;
      float val = w110[(size_t)(u * 64 + v) * NW_ + n];
      if (bu != bv) val += w110[(size_t)(v * 64 + u) * NW_ + n];
      o[j] = f2h_bits(val * s110);
    }
  }
  *(h8v*)(wf + ((size_t)s * 12 + F) * 512 + lane * 8) = *(h8v*)o;
}

// ---------------- prep: vector-path weights (f16 frags) ----------------
// layout: wf[(s*4 + nf)*512 + lane*8 + j]; s in [0,352)
//   s<256: v011 (unchanged); s>=256: v111 antisym block pairs (sp in [0,96))
__global__ void prep_wvec(const float* __restrict__ w011, const float* __restrict__ w111,
                          short* __restrict__ wf) {
  int g = blockIdx.x * blockDim.x + threadIdx.x;  // 352*4*64 = 90112 threads
  int lane = g & 63;
  int nf = (g >> 6) & 3;
  int s = g >> 8;
  int n = nf * 16 + (lane & 15);
  int kk0 = (lane >> 4) << 3;
  const float sv = 1.0f / 128.0f;
  short o[8];
  if (s < 256) {
#pragma unroll
    for (int j = 0; j < 8; ++j) {
      int k = s * 32 + kk0 + j;
      o[j] = f2h_bits(w011[(size_t)k * 64 + n] * sv);
    }
  } else {
    int sp = s - 256;
    int blk = sp >> 5, ik = sp & 31;
    int bu = tab2(PK_BU2, blk), bv = tab2(PK_BV2, blk);
    int u = bu * 32 + ik;
#pragma unroll
    for (int j = 0; j < 8; ++j) {
      int v = bv * 32 + kk0 + j;
      float val = w111[(size_t)(u * 64 + v) * 64 + n];
      if (bu != bv) val -= w111[(size_t)(v * 64 + u) * 64 + n];
      o[j] = f2h_bits(val * sv);
    }
  }
  *(h8v*)(wf + ((size_t)s * 4 + nf) * 512 + lane * 8) = *(h8v*)o;
}

// ---------------- shared LDS staging: 64 rows of x, f16 (r7-exact) ----------------
#define X0H_STRIDE 136
#define X1_STRIDE  200

DI void stage_x(const float* __restrict__ x, int b0,
                unsigned short* X0H, unsigned short* X1) {
  const int t = threadIdx.x;            // 512 threads
  const int row = t >> 3, l8 = t & 7;
  const float* src = x + (size_t)(b0 + row) * 320;
  unsigned o[8];
#pragma unroll
  for (int j = 0; j < 4; ++j) {
    f4v v = *(const f4v*)(src + l8 * 16 + j * 4);
    o[2 * j]     = hpack(v.x, v.y);
    o[2 * j + 1] = hpack(v.z, v.w);
  }
  *(u4v*)(&X0H[row * X0H_STRIDE + l8 * 16])     = u4v{o[0], o[1], o[2], o[3]};
  *(u4v*)(&X0H[row * X0H_STRIDE + l8 * 16 + 8]) = u4v{o[4], o[5], o[6], o[7]};
  float buf[24];
#pragma unroll
  for (int j = 0; j < 12; ++j) {
    f2v v = *(const f2v*)(src + 128 + l8 * 24 + j * 2);
    buf[2 * j] = v.x; buf[2 * j + 1] = v.y;
  }
#pragma unroll
  for (int i = 0; i < 3; ++i) {
    u4v w;
#pragma unroll
    for (int e = 0; e < 4; ++e)
      w[e] = hpack(buf[(2 * e) * 3 + i], buf[(2 * e + 1) * 3 + i]);
    *(u4v*)(&X1[row * X1_STRIDE + i * 64 + l8 * 8]) = w;
  }
}

DI void loadB6(h8v* dst, const short* __restrict__ p) {
#pragma unroll
  for (int nf = 0; nf < 6; ++nf) dst[nf] = *(const h8v*)(p + nf * 512);
}
DI void loadB4(h8v* dst, const short* __restrict__ p) {
#pragma unroll
  for (int nf = 0; nf < 4; ++nf) dst[nf] = *(const h8v*)(p + nf * 512);
}

// ---------------- scalar-path GEMM: C[8192,192] += A(gen) * Wsc' ----------------
// grid 512 = 128 mt x 4 kb; block 64 rows x 192 cols; 8 waves = mg2 x nh2 x kh2
// chunk c = kb*2+kh: 40 x0-pair steps + 12 dots-pair steps (416 total /8)
__global__ __launch_bounds__(512, 4)
void gemm_sc(const float* __restrict__ x, const short* __restrict__ wf,
             float* __restrict__ acc_out) {
  __shared__ unsigned short X0H[64 * X0H_STRIDE];
  __shared__ unsigned short X1[64 * X1_STRIDE];
  const int kb = blockIdx.x & 3;
  const int b0 = (blockIdx.x >> 2) * 64;

  stage_x(x, b0, X0H, X1);
  __syncthreads();

  const int t0 = threadIdx.x;
  const int w = t0 >> 6, lane = t0 & 63;
  const int mg = w & 1, nh = (w >> 1) & 1, kh = w >> 2;
  const int c = kb * 2 + kh;            // chunk 0..7
  const int q = lane >> 4, r = lane & 15, q8 = q * 8;
  const int rowA = mg * 32 + r;
  const unsigned short* x0A = &X0H[rowA * X0H_STRIDE];
  const unsigned short* x0B = &X0H[(rowA + 16) * X0H_STRIDE];
  const unsigned short* x1A = &X1[rowA * X1_STRIDE];
  const unsigned short* x1B = &X1[(rowA + 16) * X1_STRIDE];

  f4v acc[2][6];
#pragma unroll
  for (int f = 0; f < 2; ++f)
#pragma unroll
    for (int nf = 0; nf < 6; ++nf) acc[f][nf] = f4v{0.f, 0.f, 0.f, 0.f};

  // ---- region 1: x0 pair blocks, 40 steps, s in [c*40, +40) ----
  {
    const short* wp = wf + ((size_t)(c * 40) * 12 + nh * 6) * 512 + lane * 8;
    u4v pvA{}, pvB{};
    int bu32 = 0;
    for (int t = 0; t < 40; ++t) {
      const int s = c * 40 + t;
      const int ik = s & 31;
      if (t == 0 || ik == 0) {          // new 32x32 block: reload v-strip (wave-uniform)
        const int blk = s >> 5;
        const int bv32 = tab2(PK_BV0, blk) * 32;
        bu32 = tab2(PK_BU0, blk) * 32;
        pvA = *(const u4v*)(x0A + bv32 + q8);
        pvB = *(const u4v*)(x0B + bv32 + q8);
      }
      h8v b[6];
      loadB6(b, wp);
      h2v xuA = hsplat(x0A[bu32 + ik]);
      h2v xuB = hsplat(x0B[bu32 + ik]);
      u4v pa0, pa1;
#pragma unroll
      for (int m = 0; m < 4; ++m) {
        pa0[m] = hu(uh(pvA[m]) * xuA);
        pa1[m] = hu(uh(pvB[m]) * xuB);
      }
      h8v a0 = __builtin_bit_cast(h8v, pa0);
      h8v a1 = __builtin_bit_cast(h8v, pa1);
#pragma unroll
      for (int nf = 0; nf < 6; ++nf) {
        acc[0][nf] = mfma16h(a0, b[nf], acc[0][nf]);
        acc[1][nf] = mfma16h(a1, b[nf], acc[1][nf]);
      }
      wp += 6144;                        // one K-step = 12 frags x 512
    }
  }

  // ---- region 2: x1-dots pair blocks, 12 steps, sp in [c*12, +12) ----
  {
    const short* wp = wf + ((size_t)(320 + c * 12) * 12 + nh * 6) * 512 + lane * 8;
    for (int t = 0; t < 12; ++t) {
      const int sp = c * 12 + t;
      const int blk = sp >> 5, ik = sp & 31;
      const int bu32 = tab2(PK_BU2, blk) * 32;
      const int bv32 = tab2(PK_BV2, blk) * 32;
      h8v b[6];
      loadB6(b, wp);
      u4v pa0, pa1;
      {
        h2v us0 = hsplat(x1A[bu32 + ik]);
        h2v us1 = hsplat(x1A[64 + bu32 + ik]);
        h2v us2 = hsplat(x1A[128 + bu32 + ik]);
        u4v p0 = *(const u4v*)(x1A + bv32 + q8);
        u4v p1 = *(const u4v*)(x1A + 64 + bv32 + q8);
        u4v p2 = *(const u4v*)(x1A + 128 + bv32 + q8);
#pragma unroll
        for (int m = 0; m < 4; ++m) {
          h2v sm = uh(p0[m]) * us0;
          sm = sm + uh(p1[m]) * us1;
          sm = sm + uh(p2[m]) * us2;
          pa0[m] = hu(sm);
        }
      }
      {
        h2v us0 = hsplat(x1B[bu32 + ik]);
        h2v us1 = hsplat(x1B[64 + bu32 + ik]);
        h2v us2 = hsplat(x1B[128 + bu32 + ik]);
        u4v p0 = *(const u4v*)(x1B + bv32 + q8);
        u4v p1 = *(const u4v*)(x1B + 64 + bv32 + q8);
        u4v p2 = *(const u4v*)(x1B + 128 + bv32 + q8);
#pragma unroll
        for (int m = 0; m < 4; ++m) {
          h2v sm = uh(p0[m]) * us0;
          sm = sm + uh(p1[m]) * us1;
          sm = sm + uh(p2[m]) * us2;
          pa1[m] = hu(sm);
        }
      }
      h8v a0 = __builtin_bit_cast(h8v, pa0);
      h8v a1 = __builtin_bit_cast(h8v, pa1);
#pragma unroll
      for (int nf = 0; nf < 6; ++nf) {
        acc[0][nf] = mfma16h(a0, b[nf], acc[0][nf]);
        acc[1][nf] = mfma16h(a1, b[nf], acc[1][nf]);
      }
      wp += 6144;
    }
  }

#pragma unroll
  for (int f = 0; f < 2; ++f)
#pragma unroll
    for (int nf = 0; nf < 6; ++nf) {
      int n = (nh * 6 + nf) * 16 + r;
#pragma unroll
      for (int reg = 0; reg < 4; ++reg) {
        int rowo = b0 + mg * 32 + f * 16 + q * 4 + reg;
        atomicAdd(&acc_out[(size_t)rowo * NW_ + n], acc[f][nf][reg]);
      }
    }
}

// ---------------- vector-path GEMM: C[3*8192, 64] += A(gen) * Wvec' ----------------
// grid 512 = 128 mt x 4 kb; block 64 rows x 3 planes x 64 cols; 8 waves = mg4 x kh2
// chunk c: 32 v011 steps + 12 v111-pair steps (352 total /8)
__global__ __launch_bounds__(512, 4)
void gemm_vec(const float* __restrict__ x, const short* __restrict__ wf,
              float* __restrict__ acc_out) {
  __shared__ unsigned short X0H[64 * X0H_STRIDE];
  __shared__ unsigned short X1[64 * X1_STRIDE];
  const int kb = blockIdx.x & 3;
  const int b0 = (blockIdx.x >> 2) * 64;

  stage_x(x, b0, X0H, X1);
  __syncthreads();

  const int t0 = threadIdx.x;
  const int w = t0 >> 6, lane = t0 & 63;
  const int mg = w & 3, kh = w >> 2;
  const int c = kb * 2 + kh;            // chunk 0..7
  const int q = lane >> 4, r = lane & 15, q8 = q * 8;
  const int row = mg * 16 + r;
  const unsigned short* x0r = &X0H[row * X0H_STRIDE];
  const unsigned short* x1r = &X1[row * X1_STRIDE];

  f4v acc[3][4];
#pragma unroll
  for (int ip = 0; ip < 3; ++ip)
#pragma unroll
    for (int nf = 0; nf < 4; ++nf) acc[ip][nf] = f4v{0.f, 0.f, 0.f, 0.f};

  // ---- region 1: v011 (x0 * x1[ip]), 32 steps, s in [c*32, +32) (r7-exact) ----
  {
    const int u0 = c * 16;
    const short* wp = wf + (size_t)(c * 32) * 2048 + lane * 8;
    for (int g = 0; g < 16; ++g) {
      h2v xu2 = hsplat(x0r[u0 + g]);
#pragma unroll
      for (int j = 0; j < 2; ++j) {
        h8v b[4];
        loadB4(b, wp);
        const int vb = j * 32 + q8;
        h8v a[3];
#pragma unroll
        for (int i = 0; i < 3; ++i) {
          u4v p = *(const u4v*)(x1r + i * 64 + vb);
          u4v pa;
#pragma unroll
          for (int m = 0; m < 4; ++m) pa[m] = hu(uh(p[m]) * xu2);
          a[i] = __builtin_bit_cast(h8v, pa);
        }
#pragma unroll
        for (int ip = 0; ip < 3; ++ip)
#pragma unroll
          for (int nf = 0; nf < 4; ++nf)
            acc[ip][nf] = mfma16h(a[ip], b[nf], acc[ip][nf]);
        wp += 2048;                      // one K-step = 4 frags x 512
      }
    }
  }

  // ---- region 2: v111 antisym pair blocks, 12 steps, sp in [c*12, +12) ----
  {
    const short* wp = wf + (size_t)(256 + c * 12) * 2048 + lane * 8;
    for (int t = 0; t < 12; ++t) {
      const int sp = c * 12 + t;
      const int blk = sp >> 5, ik = sp & 31;
      const int bu32 = tab2(PK_BU2, blk) * 32;
      const int bv32 = tab2(PK_BV2, blk) * 32;
      h8v b[4];
      loadB4(b, wp);
      h2v us[3];
      u4v p[3];
#pragma unroll
      for (int i = 0; i < 3; ++i) {
        us[i] = hsplat(x1r[i * 64 + bu32 + ik]);
        p[i] = *(const u4v*)(x1r + i * 64 + bv32 + q8);
      }
      h8v a[3];
#pragma unroll
      for (int ip = 0; ip < 3; ++ip) {
        const int i1 = (ip + 1) % 3, i2 = (ip + 2) % 3;
        u4v pa;
#pragma unroll
        for (int m = 0; m < 4; ++m)
          pa[m] = hu(uh(p[i2][m]) * us[i1] - uh(p[i1][m]) * us[i2]);
        a[ip] = __builtin_bit_cast(h8v, pa);
      }
#pragma unroll
      for (int ip = 0; ip < 3; ++ip)
#pragma unroll
        for (int nf = 0; nf < 4; ++nf)
          acc[ip][nf] = mfma16h(a[ip], b[nf], acc[ip][nf]);
      wp += 2048;
    }
  }

#pragma unroll
  for (int ip = 0; ip < 3; ++ip)
#pragma unroll
    for (int nf = 0; nf < 4; ++nf) {
      int n = nf * 16 + r;
#pragma unroll
      for (int reg = 0; reg < 4; ++reg) {
        int rowo = ip * B_ + b0 + mg * 16 + q * 4 + reg;
        atomicAdd(&acc_out[(size_t)rowo * 64 + n], acc[ip][nf][reg]);
      }
    }
}

// ---------------- epilogue: silu / sigmoid-gating, interleaved output ----------------
__global__ void epilogue(const float* __restrict__ sc, const float* __restrict__ ve,
                         float* __restrict__ out) {
  int t = blockIdx.x * blockDim.x + threadIdx.x;  // B*192 threads exactly
  int b = t / NW_, c = t % NW_;
  float v = sc[t];
  float sg = 1.0f / (1.0f + __expf(-v));
  if (c < 128) {
    out[(size_t)b * 320 + c] = v * sg;            // silu
  } else {
    int w = c - 128;
#pragma unroll
    for (int i = 0; i < 3; ++i) {
      float vv = ve[((size_t)i * B_ + b) * 64 + w];
      out[(size_t)b * 320 + 128 + w * 3 + i] = vv * sg;
    }
  }
}

// ---------------- launch ----------------
extern "C" void kernel_launch(void* const* d_in, const int* in_sizes, int n_in,
                              void* d_out, int out_size, void* d_ws, size_t ws_size,
                              hipStream_t stream) {
  const float* x    = (const float*)d_in[0];
  const float* w000 = (const float*)d_in[1];
  const float* w110 = (const float*)d_in[2];
  const float* w011 = (const float*)d_in[3];
  const float* w111 = (const float*)d_in[4];
  float* out = (float*)d_out;

  char* ws = (char*)d_ws;
  float* acc_sc = (float*)ws;                     // 8192*192*4  = 6,291,456 B
  float* acc_ve = (float*)(ws + 6291456);         // 3*8192*64*4 = 6,291,456 B
  short* wsc    = (short*)(ws + 12582912);        // 416*12*512*2 = 5,111,808 B
  short* wve    = (short*)(ws + 17694720);        // 352*4*512*2  = 1,441,792 B
  // total ws use: 19,136,512 B

  (void)hipMemsetAsync(acc_sc, 0, 2 * 6291456, stream);  // zero both accumulators
  prep_wsc <<<1248, 256, 0, stream>>>(w000, w110, wsc);
  prep_wvec<<<352,  256, 0, stream>>>(w011, w111, wve);
  gemm_sc  <<<512, 512, 0, stream>>>(x, wsc, acc_sc);
  gemm_vec <<<512, 512, 0, stream>>>(x, wve, acc_ve);
  epilogue <<<6144, 256, 0, stream>>>(acc_sc, acc_ve, out);
}